// Round 6
// baseline (473.659 us; speedup 1.0000x reference)
//
#include <hip/hip_runtime.h>
#include <hip/hip_bf16.h>
#include <math.h>

#define D 64
#define SCAN_B 256

typedef __hip_bfloat16 bf16;

// ---------- K1: fused dst-histogram (rank capture) + xt = x @ W (bf16 out) ----
// Phase B: row index forced wave-uniform via readfirstlane so x-row loads can
// scalarize (s_load) / fully pipeline; 4 accumulator chains break the 64-deep
// FMA dependency; W in LDS (padded pitch 68, conflicts measured negligible).
__global__ __launch_bounds__(256, 8) void gemm_count_kernel(
    const float* __restrict__ x, const float* __restrict__ W,
    const int* __restrict__ ei,
    bf16* __restrict__ xt, int* __restrict__ counts, int* __restrict__ rank,
    int n_nodes, int n_edges)
{
    __shared__ float Wt[64 * 68];   // Wt[d][k] at d*68+k; 272 B row pitch

    for (int idx = threadIdx.x; idx < 4096; idx += 256) {
        int k = idx >> 6, dd = idx & 63;
        Wt[dd * 68 + k] = W[idx];
    }

    const int gid = blockIdx.x * blockDim.x + threadIdx.x;
    const int nth = gridDim.x * blockDim.x;

    // phase A: histogram of dst, capturing per-edge rank
    for (int e = gid; e < n_edges; e += nth) {
        int dst = ei[n_edges + e];
        rank[e] = atomicAdd(&counts[dst], 1);
    }

    __syncthreads();

    // phase B: one wave per row, lane d owns output column d
    const int d = threadIdx.x & 63;
    const int wid = __builtin_amdgcn_readfirstlane(gid >> 6);       // wave-uniform
    const int waves_total = nth >> 6;
    const float4* wrow = reinterpret_cast<const float4*>(&Wt[d * 68]);

    for (int row = wid; row < n_nodes; row += waves_total) {
        const float4* xr = reinterpret_cast<const float4*>(x + (size_t)row * 64);
        float a0 = 0.f, a1 = 0.f, a2 = 0.f, a3 = 0.f;
#pragma unroll
        for (int kk = 0; kk < 16; kk += 4) {
            float4 x0 = xr[kk + 0], x1 = xr[kk + 1], x2 = xr[kk + 2], x3 = xr[kk + 3];
            float4 w0 = wrow[kk + 0], w1 = wrow[kk + 1], w2 = wrow[kk + 2], w3 = wrow[kk + 3];
            a0 = fmaf(x0.x, w0.x, a0); a0 = fmaf(x0.y, w0.y, a0);
            a0 = fmaf(x0.z, w0.z, a0); a0 = fmaf(x0.w, w0.w, a0);
            a1 = fmaf(x1.x, w1.x, a1); a1 = fmaf(x1.y, w1.y, a1);
            a1 = fmaf(x1.z, w1.z, a1); a1 = fmaf(x1.w, w1.w, a1);
            a2 = fmaf(x2.x, w2.x, a2); a2 = fmaf(x2.y, w2.y, a2);
            a2 = fmaf(x2.z, w2.z, a2); a2 = fmaf(x2.w, w2.w, a2);
            a3 = fmaf(x3.x, w3.x, a3); a3 = fmaf(x3.y, w3.y, a3);
            a3 = fmaf(x3.z, w3.z, a3); a3 = fmaf(x3.w, w3.w, a3);
        }
        float acc = (a0 + a1) + (a2 + a3);
        xt[(size_t)row * 64 + d] = __float2bfloat16(acc);
    }
}

// ---------- K2: block scan (exclusive) + block totals ----------
__global__ __launch_bounds__(SCAN_B) void scan1_kernel(const int* __restrict__ c,
                                                       int* __restrict__ excl,
                                                       int* __restrict__ partials,
                                                       int n) {
    __shared__ int s[SCAN_B];
    int i = blockIdx.x * SCAN_B + threadIdx.x;
    int v = (i < n) ? c[i] : 0;
    s[threadIdx.x] = v;
    __syncthreads();
    for (int off = 1; off < SCAN_B; off <<= 1) {
        int t = (threadIdx.x >= off) ? s[threadIdx.x - off] : 0;
        __syncthreads();
        s[threadIdx.x] += t;
        __syncthreads();
    }
    if (i < n) excl[i] = s[threadIdx.x] - v;
    if (threadIdx.x == SCAN_B - 1) partials[blockIdx.x] = s[SCAN_B - 1];
}

// ---------- K3: apply partials prefix ----------
__global__ __launch_bounds__(SCAN_B) void scan23_kernel(int* __restrict__ offsets,
                                                        const int* __restrict__ partials,
                                                        int n, int n_edges) {
    __shared__ int red[SCAN_B];
    int psum = 0;
    for (int i = threadIdx.x; i < blockIdx.x; i += SCAN_B) psum += partials[i];
    red[threadIdx.x] = psum;
    __syncthreads();
    for (int off = SCAN_B / 2; off > 0; off >>= 1) {
        if (threadIdx.x < off) red[threadIdx.x] += red[threadIdx.x + off];
        __syncthreads();
    }
    int base = red[0];
    int i = blockIdx.x * SCAN_B + threadIdx.x;
    if (i < n) offsets[i] += base;
    if (blockIdx.x == 0 && threadIdx.x == 0) offsets[n] = n_edges;
}

// ---------- K4: CSR fill — NO atomics, pure dataflow scatter ----------
__global__ __launch_bounds__(256) void fill_kernel(const int* __restrict__ ei,
                                                   const float* __restrict__ ea,
                                                   const int* __restrict__ offs,
                                                   const int* __restrict__ rank,
                                                   int2* __restrict__ csr,
                                                   int n_edges) {
    int e = blockIdx.x * blockDim.x + threadIdx.x;
    if (e >= n_edges) return;
    int dst = ei[n_edges + e];
    int pos = offs[dst] + rank[e];
    long long v = ((long long)__float_as_int(ea[e]) << 32) | (unsigned)ei[e];
    __builtin_nontemporal_store(v, (long long*)(csr + pos));
}

// ---------- K5: gather, one wave per node, lane = dim, 8-wide edge ILP ------
__global__ __launch_bounds__(256) void gather_kernel(const int* __restrict__ offsets,
                                                     const int2* __restrict__ csr,
                                                     const bf16* __restrict__ xt,
                                                     const float* __restrict__ ewW,
                                                     const float* __restrict__ ewb,
                                                     const float* __restrict__ bias,
                                                     float* __restrict__ out,
                                                     int n_nodes) {
    const int d = threadIdx.x & 63;
    const int node = (blockIdx.x * blockDim.x + threadIdx.x) >> 6;
    if (node >= n_nodes) return;

    const float wd = ewW[d];
    const float bd = ewb[d];
    const int start = offsets[node];
    const int end = offsets[node + 1];

    float acc = 0.f;
    int k = start;
    for (; k + 8 <= end; k += 8) {
        long long q[8];
        float xv[8];
#pragma unroll
        for (int j = 0; j < 8; ++j)
            q[j] = __builtin_nontemporal_load((const long long*)(csr + k + j));
#pragma unroll
        for (int j = 0; j < 8; ++j)
            xv[j] = __bfloat162float(xt[(size_t)(int)(unsigned)q[j] * 64 + d]);
#pragma unroll
        for (int j = 0; j < 8; ++j) {
            float a = __int_as_float((int)(q[j] >> 32));
            float w = 1.f / (1.f + __expf(-(a * wd + bd)));
            acc = fmaf(xv[j], w, acc);
        }
    }
    for (; k + 4 <= end; k += 4) {
        long long q0 = __builtin_nontemporal_load((const long long*)(csr + k + 0));
        long long q1 = __builtin_nontemporal_load((const long long*)(csr + k + 1));
        long long q2 = __builtin_nontemporal_load((const long long*)(csr + k + 2));
        long long q3 = __builtin_nontemporal_load((const long long*)(csr + k + 3));
        float x0 = __bfloat162float(xt[(size_t)(int)(unsigned)q0 * 64 + d]);
        float x1 = __bfloat162float(xt[(size_t)(int)(unsigned)q1 * 64 + d]);
        float x2 = __bfloat162float(xt[(size_t)(int)(unsigned)q2 * 64 + d]);
        float x3 = __bfloat162float(xt[(size_t)(int)(unsigned)q3 * 64 + d]);
        float w0 = 1.f / (1.f + __expf(-(__int_as_float((int)(q0 >> 32)) * wd + bd)));
        float w1 = 1.f / (1.f + __expf(-(__int_as_float((int)(q1 >> 32)) * wd + bd)));
        float w2 = 1.f / (1.f + __expf(-(__int_as_float((int)(q2 >> 32)) * wd + bd)));
        float w3 = 1.f / (1.f + __expf(-(__int_as_float((int)(q3 >> 32)) * wd + bd)));
        acc = fmaf(x0, w0, acc);
        acc = fmaf(x1, w1, acc);
        acc = fmaf(x2, w2, acc);
        acc = fmaf(x3, w3, acc);
    }
    for (; k < end; ++k) {
        long long q = __builtin_nontemporal_load((const long long*)(csr + k));
        float xv = __bfloat162float(xt[(size_t)(int)(unsigned)q * 64 + d]);
        float a = __int_as_float((int)(q >> 32));
        float w = 1.f / (1.f + __expf(-(a * wd + bd)));
        acc = fmaf(xv, w, acc);
    }
    float r = acc + bias[d];
    __builtin_nontemporal_store(r, out + (size_t)node * 64 + d);
}

// ---------- fallback (atomic scatter) ----------
__global__ __launch_bounds__(256) void init_out_kernel(float* __restrict__ out,
                                                       const float* __restrict__ bias,
                                                       int n_f4) {
    int i = blockIdx.x * blockDim.x + threadIdx.x;
    if (i >= n_f4) return;
    float4 b4 = reinterpret_cast<const float4*>(bias)[i & 15];
    reinterpret_cast<float4*>(out)[i] = b4;
}

__global__ __launch_bounds__(256) void edge_atomic_kernel(const int* __restrict__ ei,
                                                          const float* __restrict__ ea,
                                                          const bf16* __restrict__ xt,
                                                          const float* __restrict__ ewW,
                                                          const float* __restrict__ ewb,
                                                          float* __restrict__ out,
                                                          int n_edges) {
    const int gid = blockIdx.x * blockDim.x + threadIdx.x;
    const int d0 = (gid & 15) * 4;
    int e = gid >> 4;
    const int estride = (gridDim.x * blockDim.x) >> 4;
    for (; e < n_edges; e += estride) {
        const int src = ei[e];
        const int dst = ei[n_edges + e];
        const float a = ea[e];
        float xv0 = __bfloat162float(xt[(size_t)src * 64 + d0 + 0]);
        float xv1 = __bfloat162float(xt[(size_t)src * 64 + d0 + 1]);
        float xv2 = __bfloat162float(xt[(size_t)src * 64 + d0 + 2]);
        float xv3 = __bfloat162float(xt[(size_t)src * 64 + d0 + 3]);
        float w0 = 1.f / (1.f + __expf(-(a * ewW[d0 + 0] + ewb[d0 + 0])));
        float w1 = 1.f / (1.f + __expf(-(a * ewW[d0 + 1] + ewb[d0 + 1])));
        float w2 = 1.f / (1.f + __expf(-(a * ewW[d0 + 2] + ewb[d0 + 2])));
        float w3 = 1.f / (1.f + __expf(-(a * ewW[d0 + 3] + ewb[d0 + 3])));
        float* op = out + (size_t)dst * 64 + d0;
        unsafeAtomicAdd(op + 0, xv0 * w0);
        unsafeAtomicAdd(op + 1, xv1 * w1);
        unsafeAtomicAdd(op + 2, xv2 * w2);
        unsafeAtomicAdd(op + 3, xv3 * w3);
    }
}

extern "C" void kernel_launch(void* const* d_in, const int* in_sizes, int n_in,
                              void* d_out, int out_size, void* d_ws, size_t ws_size,
                              hipStream_t stream) {
    const float* x      = (const float*)d_in[0];
    const int*   ei     = (const int*)d_in[1];
    const float* ea     = (const float*)d_in[2];
    const float* weight = (const float*)d_in[3];
    const float* ewW    = (const float*)d_in[4];
    const float* ewb    = (const float*)d_in[5];
    const float* bias   = (const float*)d_in[6];
    float* out = (float*)d_out;

    const int n_nodes = in_sizes[0] / D;   // 100000
    const int n_edges = in_sizes[2];       // 1600000

    // workspace layout
    char* ws = (char*)d_ws;
    const size_t xt_bytes   = (size_t)n_nodes * D * sizeof(bf16);      // 12.8 MB
    const size_t off_off    = (xt_bytes + 7) & ~(size_t)7;
    const size_t off_bytes  = ((size_t)n_nodes + 4) * sizeof(int);
    const size_t part_off   = off_off + off_bytes;
    const size_t part_bytes = 512 * sizeof(int);
    const size_t rank_off   = part_off + part_bytes;
    const size_t rank_bytes = (size_t)n_edges * sizeof(int);           // 6.4 MB
    size_t csr_off          = (rank_off + rank_bytes + 7) & ~(size_t)7;
    const size_t csr_bytes  = (size_t)n_edges * sizeof(int2);          // 12.8 MB
    const size_t need       = csr_off + csr_bytes;                     // ~32.5 MB

    bf16* xt   = (bf16*)(ws);
    int*  offs = (int*)(ws + off_off);
    int*  parts= (int*)(ws + part_off);
    int*  rank = (int*)(ws + rank_off);
    int2* csr  = (int2*)(ws + csr_off);

    const bool have_ws = (ws_size >= need);

    if (have_ws) {
        hipMemsetAsync(offs, 0, off_bytes, stream);
        gemm_count_kernel<<<2048, 256, 0, stream>>>(x, weight, ei, xt, offs, rank,
                                                    n_nodes, n_edges);

        const int nscan_blocks = (n_nodes + SCAN_B - 1) / SCAN_B;   // 391
        scan1_kernel<<<nscan_blocks, SCAN_B, 0, stream>>>(offs, offs, parts, n_nodes);
        scan23_kernel<<<nscan_blocks, SCAN_B, 0, stream>>>(offs, parts, n_nodes, n_edges);
        fill_kernel<<<(n_edges + 255) / 256, 256, 0, stream>>>(ei, ea, offs, rank, csr, n_edges);
        gather_kernel<<<(n_nodes * 64 + 255) / 256, 256, 0, stream>>>(offs, csr, xt, ewW, ewb,
                                                                      bias, out, n_nodes);
    } else {
        gemm_count_kernel<<<2048, 256, 0, stream>>>(x, weight, ei, xt,
                                                    /*counts=*/nullptr, /*rank=*/nullptr,
                                                    n_nodes, 0 /* skip histogram */);
        int n_f4 = n_nodes * (D / 4);
        init_out_kernel<<<(n_f4 + 255) / 256, 256, 0, stream>>>(out, bias, n_f4);
        edge_atomic_kernel<<<4096, 256, 0, stream>>>(ei, ea, xt, ewW, ewb, out, n_edges);
    }
}

// Round 7
// 462.584 us; speedup vs baseline: 1.0239x; 1.0239x over previous
//
#include <hip/hip_runtime.h>
#include <hip/hip_bf16.h>
#include <math.h>

#define D 64
#define SCAN_B 256

typedef __hip_bfloat16 bf16;

// ---------- K1a: dst-histogram with rank capture ----------
__global__ __launch_bounds__(256) void hist_kernel(const int* __restrict__ ei,
                                                   int* __restrict__ counts,
                                                   int* __restrict__ rank,
                                                   int n_edges) {
    const int gid = blockIdx.x * blockDim.x + threadIdx.x;
    const int nth = gridDim.x * blockDim.x;
    for (int e = gid; e < n_edges; e += nth) {
        int dst = ei[n_edges + e];
        rank[e] = atomicAdd(&counts[dst], 1);
    }
}

// ---------- K1b: xt = x @ W (bf16 out), W in LDS, 2 rows/wave ILP ----------
// Vector broadcast loads for x (all lanes same addr -> 1 tx via L1); NO
// readfirstlane (round-6 scalarization thrashed the scalar cache, 25x fetch).
__global__ __launch_bounds__(256, 8) void gemm_kernel(const float* __restrict__ x,
                                                      const float* __restrict__ W,
                                                      bf16* __restrict__ xt,
                                                      int n_nodes) {
    __shared__ float Wt[64 * 68];   // Wt[d][k] at d*68+k
    for (int idx = threadIdx.x; idx < 4096; idx += 256) {
        int k = idx >> 6, dd = idx & 63;
        Wt[dd * 68 + k] = W[idx];
    }
    __syncthreads();

    const int d = threadIdx.x & 63;
    const int wid = (blockIdx.x * blockDim.x + threadIdx.x) >> 6;
    const int waves_total = (gridDim.x * blockDim.x) >> 6;
    const float4* wrow = reinterpret_cast<const float4*>(&Wt[d * 68]);

    const int npairs = (n_nodes + 1) >> 1;
    for (int pair = wid; pair < npairs; pair += waves_total) {
        const int r0 = pair * 2;
        const int r1 = min(r0 + 1, n_nodes - 1);
        const float4* xa = reinterpret_cast<const float4*>(x + (size_t)r0 * 64);
        const float4* xb = reinterpret_cast<const float4*>(x + (size_t)r1 * 64);
        float accA0 = 0.f, accA1 = 0.f, accB0 = 0.f, accB1 = 0.f;
#pragma unroll
        for (int kk = 0; kk < 16; kk += 2) {
            float4 wa = wrow[kk], wb = wrow[kk + 1];
            float4 xa0 = xa[kk], xa1 = xa[kk + 1];
            float4 xb0 = xb[kk], xb1 = xb[kk + 1];
            accA0 = fmaf(xa0.x, wa.x, accA0); accA0 = fmaf(xa0.y, wa.y, accA0);
            accA0 = fmaf(xa0.z, wa.z, accA0); accA0 = fmaf(xa0.w, wa.w, accA0);
            accB0 = fmaf(xb0.x, wa.x, accB0); accB0 = fmaf(xb0.y, wa.y, accB0);
            accB0 = fmaf(xb0.z, wa.z, accB0); accB0 = fmaf(xb0.w, wa.w, accB0);
            accA1 = fmaf(xa1.x, wb.x, accA1); accA1 = fmaf(xa1.y, wb.y, accA1);
            accA1 = fmaf(xa1.z, wb.z, accA1); accA1 = fmaf(xa1.w, wb.w, accA1);
            accB1 = fmaf(xb1.x, wb.x, accB1); accB1 = fmaf(xb1.y, wb.y, accB1);
            accB1 = fmaf(xb1.z, wb.z, accB1); accB1 = fmaf(xb1.w, wb.w, accB1);
        }
        xt[(size_t)r0 * 64 + d] = __float2bfloat16(accA0 + accA1);
        if (r1 != r0)
            xt[(size_t)r1 * 64 + d] = __float2bfloat16(accB0 + accB1);
    }
}

// ---------- K2: block scan (exclusive) + block totals ----------
__global__ __launch_bounds__(SCAN_B) void scan1_kernel(const int* __restrict__ c,
                                                       int* __restrict__ excl,
                                                       int* __restrict__ partials,
                                                       int n) {
    __shared__ int s[SCAN_B];
    int i = blockIdx.x * SCAN_B + threadIdx.x;
    int v = (i < n) ? c[i] : 0;
    s[threadIdx.x] = v;
    __syncthreads();
    for (int off = 1; off < SCAN_B; off <<= 1) {
        int t = (threadIdx.x >= off) ? s[threadIdx.x - off] : 0;
        __syncthreads();
        s[threadIdx.x] += t;
        __syncthreads();
    }
    if (i < n) excl[i] = s[threadIdx.x] - v;
    if (threadIdx.x == SCAN_B - 1) partials[blockIdx.x] = s[SCAN_B - 1];
}

// ---------- K3: apply partials prefix ----------
__global__ __launch_bounds__(SCAN_B) void scan23_kernel(int* __restrict__ offsets,
                                                        const int* __restrict__ partials,
                                                        int n, int n_edges) {
    __shared__ int red[SCAN_B];
    int psum = 0;
    for (int i = threadIdx.x; i < blockIdx.x; i += SCAN_B) psum += partials[i];
    red[threadIdx.x] = psum;
    __syncthreads();
    for (int off = SCAN_B / 2; off > 0; off >>= 1) {
        if (threadIdx.x < off) red[threadIdx.x] += red[threadIdx.x + off];
        __syncthreads();
    }
    int base = red[0];
    int i = blockIdx.x * SCAN_B + threadIdx.x;
    if (i < n) offsets[i] += base;
    if (blockIdx.x == 0 && threadIdx.x == 0) offsets[n] = n_edges;
}

// ---------- K4: CSR fill — NO atomics, pure dataflow scatter ----------
__global__ __launch_bounds__(256) void fill_kernel(const int* __restrict__ ei,
                                                   const float* __restrict__ ea,
                                                   const int* __restrict__ offs,
                                                   const int* __restrict__ rank,
                                                   int2* __restrict__ csr,
                                                   int n_edges) {
    int e = blockIdx.x * blockDim.x + threadIdx.x;
    if (e >= n_edges) return;
    int dst = ei[n_edges + e];
    int pos = offs[dst] + rank[e];
    long long v = ((long long)__float_as_int(ea[e]) << 32) | (unsigned)ei[e];
    __builtin_nontemporal_store(v, (long long*)(csr + pos));
}

// ---------- K5: gather, one wave per node, lane = dim, 8-wide edge ILP ------
__global__ __launch_bounds__(256) void gather_kernel(const int* __restrict__ offsets,
                                                     const int2* __restrict__ csr,
                                                     const bf16* __restrict__ xt,
                                                     const float* __restrict__ ewW,
                                                     const float* __restrict__ ewb,
                                                     const float* __restrict__ bias,
                                                     float* __restrict__ out,
                                                     int n_nodes) {
    const int d = threadIdx.x & 63;
    const int node = (blockIdx.x * blockDim.x + threadIdx.x) >> 6;
    if (node >= n_nodes) return;

    const float wd = ewW[d];
    const float bd = ewb[d];
    const int start = offsets[node];
    const int end = offsets[node + 1];

    float acc = 0.f;
    int k = start;
    for (; k + 8 <= end; k += 8) {
        long long q[8];
        float xv[8];
#pragma unroll
        for (int j = 0; j < 8; ++j)
            q[j] = __builtin_nontemporal_load((const long long*)(csr + k + j));
#pragma unroll
        for (int j = 0; j < 8; ++j)
            xv[j] = __bfloat162float(xt[(size_t)(int)(unsigned)q[j] * 64 + d]);
#pragma unroll
        for (int j = 0; j < 8; ++j) {
            float a = __int_as_float((int)(q[j] >> 32));
            float w = 1.f / (1.f + __expf(-(a * wd + bd)));
            acc = fmaf(xv[j], w, acc);
        }
    }
    for (; k + 4 <= end; k += 4) {
        long long q0 = __builtin_nontemporal_load((const long long*)(csr + k + 0));
        long long q1 = __builtin_nontemporal_load((const long long*)(csr + k + 1));
        long long q2 = __builtin_nontemporal_load((const long long*)(csr + k + 2));
        long long q3 = __builtin_nontemporal_load((const long long*)(csr + k + 3));
        float x0 = __bfloat162float(xt[(size_t)(int)(unsigned)q0 * 64 + d]);
        float x1 = __bfloat162float(xt[(size_t)(int)(unsigned)q1 * 64 + d]);
        float x2 = __bfloat162float(xt[(size_t)(int)(unsigned)q2 * 64 + d]);
        float x3 = __bfloat162float(xt[(size_t)(int)(unsigned)q3 * 64 + d]);
        float w0 = 1.f / (1.f + __expf(-(__int_as_float((int)(q0 >> 32)) * wd + bd)));
        float w1 = 1.f / (1.f + __expf(-(__int_as_float((int)(q1 >> 32)) * wd + bd)));
        float w2 = 1.f / (1.f + __expf(-(__int_as_float((int)(q2 >> 32)) * wd + bd)));
        float w3 = 1.f / (1.f + __expf(-(__int_as_float((int)(q3 >> 32)) * wd + bd)));
        acc = fmaf(x0, w0, acc);
        acc = fmaf(x1, w1, acc);
        acc = fmaf(x2, w2, acc);
        acc = fmaf(x3, w3, acc);
    }
    for (; k < end; ++k) {
        long long q = __builtin_nontemporal_load((const long long*)(csr + k));
        float xv = __bfloat162float(xt[(size_t)(int)(unsigned)q * 64 + d]);
        float a = __int_as_float((int)(q >> 32));
        float w = 1.f / (1.f + __expf(-(a * wd + bd)));
        acc = fmaf(xv, w, acc);
    }
    float r = acc + bias[d];
    __builtin_nontemporal_store(r, out + (size_t)node * 64 + d);
}

// ---------- fallback (atomic scatter) ----------
__global__ __launch_bounds__(256) void init_out_kernel(float* __restrict__ out,
                                                       const float* __restrict__ bias,
                                                       int n_f4) {
    int i = blockIdx.x * blockDim.x + threadIdx.x;
    if (i >= n_f4) return;
    float4 b4 = reinterpret_cast<const float4*>(bias)[i & 15];
    reinterpret_cast<float4*>(out)[i] = b4;
}

__global__ __launch_bounds__(256) void edge_atomic_kernel(const int* __restrict__ ei,
                                                          const float* __restrict__ ea,
                                                          const bf16* __restrict__ xt,
                                                          const float* __restrict__ ewW,
                                                          const float* __restrict__ ewb,
                                                          float* __restrict__ out,
                                                          int n_edges) {
    const int gid = blockIdx.x * blockDim.x + threadIdx.x;
    const int d0 = (gid & 15) * 4;
    int e = gid >> 4;
    const int estride = (gridDim.x * blockDim.x) >> 4;
    for (; e < n_edges; e += estride) {
        const int src = ei[e];
        const int dst = ei[n_edges + e];
        const float a = ea[e];
        float xv0 = __bfloat162float(xt[(size_t)src * 64 + d0 + 0]);
        float xv1 = __bfloat162float(xt[(size_t)src * 64 + d0 + 1]);
        float xv2 = __bfloat162float(xt[(size_t)src * 64 + d0 + 2]);
        float xv3 = __bfloat162float(xt[(size_t)src * 64 + d0 + 3]);
        float w0 = 1.f / (1.f + __expf(-(a * ewW[d0 + 0] + ewb[d0 + 0])));
        float w1 = 1.f / (1.f + __expf(-(a * ewW[d0 + 1] + ewb[d0 + 1])));
        float w2 = 1.f / (1.f + __expf(-(a * ewW[d0 + 2] + ewb[d0 + 2])));
        float w3 = 1.f / (1.f + __expf(-(a * ewW[d0 + 3] + ewb[d0 + 3])));
        float* op = out + (size_t)dst * 64 + d0;
        unsafeAtomicAdd(op + 0, xv0 * w0);
        unsafeAtomicAdd(op + 1, xv1 * w1);
        unsafeAtomicAdd(op + 2, xv2 * w2);
        unsafeAtomicAdd(op + 3, xv3 * w3);
    }
}

extern "C" void kernel_launch(void* const* d_in, const int* in_sizes, int n_in,
                              void* d_out, int out_size, void* d_ws, size_t ws_size,
                              hipStream_t stream) {
    const float* x      = (const float*)d_in[0];
    const int*   ei     = (const int*)d_in[1];
    const float* ea     = (const float*)d_in[2];
    const float* weight = (const float*)d_in[3];
    const float* ewW    = (const float*)d_in[4];
    const float* ewb    = (const float*)d_in[5];
    const float* bias   = (const float*)d_in[6];
    float* out = (float*)d_out;

    const int n_nodes = in_sizes[0] / D;   // 100000
    const int n_edges = in_sizes[2];       // 1600000

    // workspace layout
    char* ws = (char*)d_ws;
    const size_t xt_bytes   = (size_t)n_nodes * D * sizeof(bf16);      // 12.8 MB
    const size_t off_off    = (xt_bytes + 7) & ~(size_t)7;
    const size_t off_bytes  = ((size_t)n_nodes + 4) * sizeof(int);
    const size_t part_off   = off_off + off_bytes;
    const size_t part_bytes = 512 * sizeof(int);
    const size_t rank_off   = part_off + part_bytes;
    const size_t rank_bytes = (size_t)n_edges * sizeof(int);           // 6.4 MB
    size_t csr_off          = (rank_off + rank_bytes + 7) & ~(size_t)7;
    const size_t csr_bytes  = (size_t)n_edges * sizeof(int2);          // 12.8 MB
    const size_t need       = csr_off + csr_bytes;                     // ~32.5 MB

    bf16* xt   = (bf16*)(ws);
    int*  offs = (int*)(ws + off_off);
    int*  parts= (int*)(ws + part_off);
    int*  rank = (int*)(ws + rank_off);
    int2* csr  = (int2*)(ws + csr_off);

    const bool have_ws = (ws_size >= need);

    if (have_ws) {
        hipMemsetAsync(offs, 0, off_bytes, stream);
        hist_kernel<<<2048, 256, 0, stream>>>(ei, offs, rank, n_edges);
        gemm_kernel<<<2048, 256, 0, stream>>>(x, weight, xt, n_nodes);

        const int nscan_blocks = (n_nodes + SCAN_B - 1) / SCAN_B;   // 391
        scan1_kernel<<<nscan_blocks, SCAN_B, 0, stream>>>(offs, offs, parts, n_nodes);
        scan23_kernel<<<nscan_blocks, SCAN_B, 0, stream>>>(offs, parts, n_nodes, n_edges);
        fill_kernel<<<(n_edges + 255) / 256, 256, 0, stream>>>(ei, ea, offs, rank, csr, n_edges);
        gather_kernel<<<(n_nodes * 64 + 255) / 256, 256, 0, stream>>>(offs, csr, xt, ewW, ewb,
                                                                      bias, out, n_nodes);
    } else {
        gemm_kernel<<<2048, 256, 0, stream>>>(x, weight, xt, n_nodes);
        int n_f4 = n_nodes * (D / 4);
        init_out_kernel<<<(n_f4 + 255) / 256, 256, 0, stream>>>(out, bias, n_f4);
        edge_atomic_kernel<<<4096, 256, 0, stream>>>(ei, ea, xt, ewW, ewb, out, n_edges);
    }
}

// Round 8
// 220.201 us; speedup vs baseline: 2.1510x; 2.1007x over previous
//
#include <hip/hip_runtime.h>
#include <hip/hip_bf16.h>
#include <math.h>

#define D 64
#define SCAN_B 256

typedef __hip_bfloat16 bf16;
typedef __attribute__((ext_vector_type(8))) short bf16x8;   // 8 bf16 (4 VGPRs)
typedef __attribute__((ext_vector_type(4))) float f32x4;

static __device__ __forceinline__ short f2bf(float f) {
    unsigned u = __float_as_uint(f);
    u = (u + 0x7FFFu + ((u >> 16) & 1u)) >> 16;   // RNE
    return (short)u;
}

// ---------- K1a: dst-histogram with rank capture ----------
__global__ __launch_bounds__(256) void hist_kernel(const int* __restrict__ ei,
                                                   int* __restrict__ counts,
                                                   int* __restrict__ rank,
                                                   int n_edges) {
    const int gid = blockIdx.x * blockDim.x + threadIdx.x;
    const int nth = gridDim.x * blockDim.x;
    for (int e = gid; e < n_edges; e += nth) {
        int dst = ei[n_edges + e];
        rank[e] = atomicAdd(&counts[dst], 1);
    }
}

// ---------- K1b: xt = x @ W via MFMA (bf16 inputs, fp32 accum, bf16 out) ----
// 4 waves/block; wave handles 16 rows x 64 cols via 4 col-tiles x 2 K-halves
// of v_mfma_f32_16x16x32_bf16. A loads: lanes {i,i+16,i+32,i+48} cover one
// row's 128B K-half contiguously -> fully coalesced, no broadcast loads.
__global__ __launch_bounds__(256) void gemm_mfma_kernel(const float* __restrict__ x,
                                                        const float* __restrict__ W,
                                                        bf16* __restrict__ xt,
                                                        int n_nodes) {
    __shared__ float Ws[64 * 64];
    {
        const float4* src = reinterpret_cast<const float4*>(W);
        float4* dstp = reinterpret_cast<float4*>(Ws);
        for (int i = threadIdx.x; i < 1024; i += 256) dstp[i] = src[i];
    }
    __syncthreads();

    const int lane  = threadIdx.x & 63;
    const int wv    = threadIdx.x >> 6;          // 0..3
    const int m0    = blockIdx.x * 64 + wv * 16; // wave's first output row
    const int half  = lane >> 4;                 // 0..3
    const int idx16 = lane & 15;
    const int k0    = half * 8;

    // B fragments: lane holds B[k = h*32 + k0 + j][n = t*16 + idx16]
    bf16x8 bfrag[4][2];
#pragma unroll
    for (int t = 0; t < 4; ++t) {
#pragma unroll
        for (int h = 0; h < 2; ++h) {
            bf16x8 f;
#pragma unroll
            for (int j = 0; j < 8; ++j)
                f[j] = f2bf(Ws[(h * 32 + k0 + j) * 64 + t * 16 + idx16]);
            bfrag[t][h] = f;
        }
    }

    const int am = m0 + idx16;                   // A row for this lane
    const bool valid = (am < n_nodes);
    const float* arow = x + (size_t)(valid ? am : 0) * 64;

    f32x4 acc[4] = {{0.f, 0.f, 0.f, 0.f}, {0.f, 0.f, 0.f, 0.f},
                    {0.f, 0.f, 0.f, 0.f}, {0.f, 0.f, 0.f, 0.f}};

#pragma unroll
    for (int h = 0; h < 2; ++h) {
        bf16x8 afrag = {0, 0, 0, 0, 0, 0, 0, 0};
        if (valid) {
            float4 p0 = *reinterpret_cast<const float4*>(arow + h * 32 + k0);
            float4 p1 = *reinterpret_cast<const float4*>(arow + h * 32 + k0 + 4);
            afrag[0] = f2bf(p0.x); afrag[1] = f2bf(p0.y);
            afrag[2] = f2bf(p0.z); afrag[3] = f2bf(p0.w);
            afrag[4] = f2bf(p1.x); afrag[5] = f2bf(p1.y);
            afrag[6] = f2bf(p1.z); afrag[7] = f2bf(p1.w);
        }
#pragma unroll
        for (int t = 0; t < 4; ++t)
            acc[t] = __builtin_amdgcn_mfma_f32_16x16x32_bf16(afrag, bfrag[t][h],
                                                             acc[t], 0, 0, 0);
    }

    // D: row = m0 + half*4 + r, col = t*16 + idx16
    const int srow0 = m0 + half * 4;
#pragma unroll
    for (int r = 0; r < 4; ++r) {
        int row = srow0 + r;
        if (row < n_nodes) {
#pragma unroll
            for (int t = 0; t < 4; ++t)
                xt[(size_t)row * 64 + t * 16 + idx16] = __float2bfloat16(acc[t][r]);
        }
    }
}

// ---------- K2: block scan (exclusive) + block totals ----------
__global__ __launch_bounds__(SCAN_B) void scan1_kernel(const int* __restrict__ c,
                                                       int* __restrict__ excl,
                                                       int* __restrict__ partials,
                                                       int n) {
    __shared__ int s[SCAN_B];
    int i = blockIdx.x * SCAN_B + threadIdx.x;
    int v = (i < n) ? c[i] : 0;
    s[threadIdx.x] = v;
    __syncthreads();
    for (int off = 1; off < SCAN_B; off <<= 1) {
        int t = (threadIdx.x >= off) ? s[threadIdx.x - off] : 0;
        __syncthreads();
        s[threadIdx.x] += t;
        __syncthreads();
    }
    if (i < n) excl[i] = s[threadIdx.x] - v;
    if (threadIdx.x == SCAN_B - 1) partials[blockIdx.x] = s[SCAN_B - 1];
}

// ---------- K3: apply partials prefix ----------
__global__ __launch_bounds__(SCAN_B) void scan23_kernel(int* __restrict__ offsets,
                                                        const int* __restrict__ partials,
                                                        int n, int n_edges) {
    __shared__ int red[SCAN_B];
    int psum = 0;
    for (int i = threadIdx.x; i < blockIdx.x; i += SCAN_B) psum += partials[i];
    red[threadIdx.x] = psum;
    __syncthreads();
    for (int off = SCAN_B / 2; off > 0; off >>= 1) {
        if (threadIdx.x < off) red[threadIdx.x] += red[threadIdx.x + off];
        __syncthreads();
    }
    int base = red[0];
    int i = blockIdx.x * SCAN_B + threadIdx.x;
    if (i < n) offsets[i] += base;
    if (blockIdx.x == 0 && threadIdx.x == 0) offsets[n] = n_edges;
}

// ---------- K4: CSR fill — NO atomics, pure dataflow scatter ----------
__global__ __launch_bounds__(256) void fill_kernel(const int* __restrict__ ei,
                                                   const float* __restrict__ ea,
                                                   const int* __restrict__ offs,
                                                   const int* __restrict__ rank,
                                                   int2* __restrict__ csr,
                                                   int n_edges) {
    int e = blockIdx.x * blockDim.x + threadIdx.x;
    if (e >= n_edges) return;
    int dst = ei[n_edges + e];
    int pos = offs[dst] + rank[e];
    long long v = ((long long)__float_as_int(ea[e]) << 32) | (unsigned)ei[e];
    __builtin_nontemporal_store(v, (long long*)(csr + pos));
}

// ---------- K5: gather, one wave per node, lane = dim, 8-wide edge ILP ------
__global__ __launch_bounds__(256) void gather_kernel(const int* __restrict__ offsets,
                                                     const int2* __restrict__ csr,
                                                     const bf16* __restrict__ xt,
                                                     const float* __restrict__ ewW,
                                                     const float* __restrict__ ewb,
                                                     const float* __restrict__ bias,
                                                     float* __restrict__ out,
                                                     int n_nodes) {
    const int d = threadIdx.x & 63;
    const int node = (blockIdx.x * blockDim.x + threadIdx.x) >> 6;
    if (node >= n_nodes) return;

    const float wd = ewW[d];
    const float bd = ewb[d];
    const int start = offsets[node];
    const int end = offsets[node + 1];

    float acc = 0.f;
    int k = start;
    for (; k + 8 <= end; k += 8) {
        long long q[8];
        float xv[8];
#pragma unroll
        for (int j = 0; j < 8; ++j)
            q[j] = __builtin_nontemporal_load((const long long*)(csr + k + j));
#pragma unroll
        for (int j = 0; j < 8; ++j)
            xv[j] = __bfloat162float(xt[(size_t)(int)(unsigned)q[j] * 64 + d]);
#pragma unroll
        for (int j = 0; j < 8; ++j) {
            float a = __int_as_float((int)(q[j] >> 32));
            float w = 1.f / (1.f + __expf(-(a * wd + bd)));
            acc = fmaf(xv[j], w, acc);
        }
    }
    for (; k + 4 <= end; k += 4) {
        long long q0 = __builtin_nontemporal_load((const long long*)(csr + k + 0));
        long long q1 = __builtin_nontemporal_load((const long long*)(csr + k + 1));
        long long q2 = __builtin_nontemporal_load((const long long*)(csr + k + 2));
        long long q3 = __builtin_nontemporal_load((const long long*)(csr + k + 3));
        float x0 = __bfloat162float(xt[(size_t)(int)(unsigned)q0 * 64 + d]);
        float x1 = __bfloat162float(xt[(size_t)(int)(unsigned)q1 * 64 + d]);
        float x2 = __bfloat162float(xt[(size_t)(int)(unsigned)q2 * 64 + d]);
        float x3 = __bfloat162float(xt[(size_t)(int)(unsigned)q3 * 64 + d]);
        float w0 = 1.f / (1.f + __expf(-(__int_as_float((int)(q0 >> 32)) * wd + bd)));
        float w1 = 1.f / (1.f + __expf(-(__int_as_float((int)(q1 >> 32)) * wd + bd)));
        float w2 = 1.f / (1.f + __expf(-(__int_as_float((int)(q2 >> 32)) * wd + bd)));
        float w3 = 1.f / (1.f + __expf(-(__int_as_float((int)(q3 >> 32)) * wd + bd)));
        acc = fmaf(x0, w0, acc);
        acc = fmaf(x1, w1, acc);
        acc = fmaf(x2, w2, acc);
        acc = fmaf(x3, w3, acc);
    }
    for (; k < end; ++k) {
        long long q = __builtin_nontemporal_load((const long long*)(csr + k));
        float xv = __bfloat162float(xt[(size_t)(int)(unsigned)q * 64 + d]);
        float a = __int_as_float((int)(q >> 32));
        float w = 1.f / (1.f + __expf(-(a * wd + bd)));
        acc = fmaf(xv, w, acc);
    }
    float r = acc + bias[d];
    __builtin_nontemporal_store(r, out + (size_t)node * 64 + d);
}

// ---------- fallback (atomic scatter) ----------
__global__ __launch_bounds__(256) void init_out_kernel(float* __restrict__ out,
                                                       const float* __restrict__ bias,
                                                       int n_f4) {
    int i = blockIdx.x * blockDim.x + threadIdx.x;
    if (i >= n_f4) return;
    float4 b4 = reinterpret_cast<const float4*>(bias)[i & 15];
    reinterpret_cast<float4*>(out)[i] = b4;
}

__global__ __launch_bounds__(256) void edge_atomic_kernel(const int* __restrict__ ei,
                                                          const float* __restrict__ ea,
                                                          const bf16* __restrict__ xt,
                                                          const float* __restrict__ ewW,
                                                          const float* __restrict__ ewb,
                                                          float* __restrict__ out,
                                                          int n_edges) {
    const int gid = blockIdx.x * blockDim.x + threadIdx.x;
    const int d0 = (gid & 15) * 4;
    int e = gid >> 4;
    const int estride = (gridDim.x * blockDim.x) >> 4;
    for (; e < n_edges; e += estride) {
        const int src = ei[e];
        const int dst = ei[n_edges + e];
        const float a = ea[e];
        float xv0 = __bfloat162float(xt[(size_t)src * 64 + d0 + 0]);
        float xv1 = __bfloat162float(xt[(size_t)src * 64 + d0 + 1]);
        float xv2 = __bfloat162float(xt[(size_t)src * 64 + d0 + 2]);
        float xv3 = __bfloat162float(xt[(size_t)src * 64 + d0 + 3]);
        float w0 = 1.f / (1.f + __expf(-(a * ewW[d0 + 0] + ewb[d0 + 0])));
        float w1 = 1.f / (1.f + __expf(-(a * ewW[d0 + 1] + ewb[d0 + 1])));
        float w2 = 1.f / (1.f + __expf(-(a * ewW[d0 + 2] + ewb[d0 + 2])));
        float w3 = 1.f / (1.f + __expf(-(a * ewW[d0 + 3] + ewb[d0 + 3])));
        float* op = out + (size_t)dst * 64 + d0;
        unsafeAtomicAdd(op + 0, xv0 * w0);
        unsafeAtomicAdd(op + 1, xv1 * w1);
        unsafeAtomicAdd(op + 2, xv2 * w2);
        unsafeAtomicAdd(op + 3, xv3 * w3);
    }
}

extern "C" void kernel_launch(void* const* d_in, const int* in_sizes, int n_in,
                              void* d_out, int out_size, void* d_ws, size_t ws_size,
                              hipStream_t stream) {
    const float* x      = (const float*)d_in[0];
    const int*   ei     = (const int*)d_in[1];
    const float* ea     = (const float*)d_in[2];
    const float* weight = (const float*)d_in[3];
    const float* ewW    = (const float*)d_in[4];
    const float* ewb    = (const float*)d_in[5];
    const float* bias   = (const float*)d_in[6];
    float* out = (float*)d_out;

    const int n_nodes = in_sizes[0] / D;   // 100000
    const int n_edges = in_sizes[2];       // 1600000

    // workspace layout
    char* ws = (char*)d_ws;
    const size_t xt_bytes   = (size_t)n_nodes * D * sizeof(bf16);      // 12.8 MB
    const size_t off_off    = (xt_bytes + 7) & ~(size_t)7;
    const size_t off_bytes  = ((size_t)n_nodes + 4) * sizeof(int);
    const size_t part_off   = off_off + off_bytes;
    const size_t part_bytes = 512 * sizeof(int);
    const size_t rank_off   = part_off + part_bytes;
    const size_t rank_bytes = (size_t)n_edges * sizeof(int);           // 6.4 MB
    size_t csr_off          = (rank_off + rank_bytes + 7) & ~(size_t)7;
    const size_t csr_bytes  = (size_t)n_edges * sizeof(int2);          // 12.8 MB
    const size_t need       = csr_off + csr_bytes;                     // ~32.5 MB

    bf16* xt   = (bf16*)(ws);
    int*  offs = (int*)(ws + off_off);
    int*  parts= (int*)(ws + part_off);
    int*  rank = (int*)(ws + rank_off);
    int2* csr  = (int2*)(ws + csr_off);

    const bool have_ws = (ws_size >= need);
    const int gemm_grid = (n_nodes + 63) / 64;   // 1563

    if (have_ws) {
        hipMemsetAsync(offs, 0, off_bytes, stream);
        hist_kernel<<<2048, 256, 0, stream>>>(ei, offs, rank, n_edges);
        gemm_mfma_kernel<<<gemm_grid, 256, 0, stream>>>(x, weight, xt, n_nodes);

        const int nscan_blocks = (n_nodes + SCAN_B - 1) / SCAN_B;   // 391
        scan1_kernel<<<nscan_blocks, SCAN_B, 0, stream>>>(offs, offs, parts, n_nodes);
        scan23_kernel<<<nscan_blocks, SCAN_B, 0, stream>>>(offs, parts, n_nodes, n_edges);
        fill_kernel<<<(n_edges + 255) / 256, 256, 0, stream>>>(ei, ea, offs, rank, csr, n_edges);
        gather_kernel<<<(n_nodes * 64 + 255) / 256, 256, 0, stream>>>(offs, csr, xt, ewW, ewb,
                                                                      bias, out, n_nodes);
    } else {
        gemm_mfma_kernel<<<gemm_grid, 256, 0, stream>>>(x, weight, xt, n_nodes);
        int n_f4 = n_nodes * (D / 4);
        init_out_kernel<<<(n_f4 + 255) / 256, 256, 0, stream>>>(out, bias, n_f4);
        edge_atomic_kernel<<<4096, 256, 0, stream>>>(ei, ea, xt, ewW, ewb, out, n_edges);
    }
}

// Round 9
// 214.051 us; speedup vs baseline: 2.2128x; 1.0287x over previous
//
#include <hip/hip_runtime.h>
#include <hip/hip_bf16.h>
#include <math.h>

#define D 64
#define SCAN_B 256

typedef __hip_bfloat16 bf16;
typedef __attribute__((ext_vector_type(8))) short bf16x8;   // 8 bf16 (4 VGPRs)
typedef __attribute__((ext_vector_type(4))) float f32x4;

static __device__ __forceinline__ short f2bf(float f) {
    unsigned u = __float_as_uint(f);
    u = (u + 0x7FFFu + ((u >> 16) & 1u)) >> 16;   // RNE
    return (short)u;
}

// fast sigmoid: rcp approx instead of precise-division fixup sequence
static __device__ __forceinline__ float fsig(float a, float nwd, float nbd) {
    float e = __expf(fmaf(a, nwd, nbd));          // exp(-(a*wd+bd))
    return __builtin_amdgcn_rcpf(1.f + e);
}

// ---------- K1a: dst-histogram with rank capture ----------
__global__ __launch_bounds__(256) void hist_kernel(const int* __restrict__ ei,
                                                   int* __restrict__ counts,
                                                   int* __restrict__ rank,
                                                   int n_edges) {
    const int gid = blockIdx.x * blockDim.x + threadIdx.x;
    const int nth = gridDim.x * blockDim.x;
    for (int e = gid; e < n_edges; e += nth) {
        int dst = ei[n_edges + e];
        rank[e] = atomicAdd(&counts[dst], 1);
    }
}

// ---------- K1b: xt = x @ W via MFMA (bf16 inputs, fp32 accum, bf16 out) ----
__global__ __launch_bounds__(256) void gemm_mfma_kernel(const float* __restrict__ x,
                                                        const float* __restrict__ W,
                                                        bf16* __restrict__ xt,
                                                        int n_nodes) {
    __shared__ float Ws[64 * 64];
    {
        const float4* src = reinterpret_cast<const float4*>(W);
        float4* dstp = reinterpret_cast<float4*>(Ws);
        for (int i = threadIdx.x; i < 1024; i += 256) dstp[i] = src[i];
    }
    __syncthreads();

    const int lane  = threadIdx.x & 63;
    const int wv    = threadIdx.x >> 6;          // 0..3
    const int m0    = blockIdx.x * 64 + wv * 16; // wave's first output row
    const int half  = lane >> 4;                 // 0..3
    const int idx16 = lane & 15;
    const int k0    = half * 8;

    bf16x8 bfrag[4][2];
#pragma unroll
    for (int t = 0; t < 4; ++t) {
#pragma unroll
        for (int h = 0; h < 2; ++h) {
            bf16x8 f;
#pragma unroll
            for (int j = 0; j < 8; ++j)
                f[j] = f2bf(Ws[(h * 32 + k0 + j) * 64 + t * 16 + idx16]);
            bfrag[t][h] = f;
        }
    }

    const int am = m0 + idx16;
    const bool valid = (am < n_nodes);
    const float* arow = x + (size_t)(valid ? am : 0) * 64;

    f32x4 acc[4] = {{0.f, 0.f, 0.f, 0.f}, {0.f, 0.f, 0.f, 0.f},
                    {0.f, 0.f, 0.f, 0.f}, {0.f, 0.f, 0.f, 0.f}};

#pragma unroll
    for (int h = 0; h < 2; ++h) {
        bf16x8 afrag = {0, 0, 0, 0, 0, 0, 0, 0};
        if (valid) {
            float4 p0 = *reinterpret_cast<const float4*>(arow + h * 32 + k0);
            float4 p1 = *reinterpret_cast<const float4*>(arow + h * 32 + k0 + 4);
            afrag[0] = f2bf(p0.x); afrag[1] = f2bf(p0.y);
            afrag[2] = f2bf(p0.z); afrag[3] = f2bf(p0.w);
            afrag[4] = f2bf(p1.x); afrag[5] = f2bf(p1.y);
            afrag[6] = f2bf(p1.z); afrag[7] = f2bf(p1.w);
        }
#pragma unroll
        for (int t = 0; t < 4; ++t)
            acc[t] = __builtin_amdgcn_mfma_f32_16x16x32_bf16(afrag, bfrag[t][h],
                                                             acc[t], 0, 0, 0);
    }

    const int srow0 = m0 + half * 4;
#pragma unroll
    for (int r = 0; r < 4; ++r) {
        int row = srow0 + r;
        if (row < n_nodes) {
#pragma unroll
            for (int t = 0; t < 4; ++t)
                xt[(size_t)row * 64 + t * 16 + idx16] = __float2bfloat16(acc[t][r]);
        }
    }
}

// ---------- K2: block scan (exclusive) + block totals ----------
__global__ __launch_bounds__(SCAN_B) void scan1_kernel(const int* __restrict__ c,
                                                       int* __restrict__ excl,
                                                       int* __restrict__ partials,
                                                       int n) {
    __shared__ int s[SCAN_B];
    int i = blockIdx.x * SCAN_B + threadIdx.x;
    int v = (i < n) ? c[i] : 0;
    s[threadIdx.x] = v;
    __syncthreads();
    for (int off = 1; off < SCAN_B; off <<= 1) {
        int t = (threadIdx.x >= off) ? s[threadIdx.x - off] : 0;
        __syncthreads();
        s[threadIdx.x] += t;
        __syncthreads();
    }
    if (i < n) excl[i] = s[threadIdx.x] - v;
    if (threadIdx.x == SCAN_B - 1) partials[blockIdx.x] = s[SCAN_B - 1];
}

// ---------- K3: apply partials prefix ----------
__global__ __launch_bounds__(SCAN_B) void scan23_kernel(int* __restrict__ offsets,
                                                        const int* __restrict__ partials,
                                                        int n, int n_edges) {
    __shared__ int red[SCAN_B];
    int psum = 0;
    for (int i = threadIdx.x; i < blockIdx.x; i += SCAN_B) psum += partials[i];
    red[threadIdx.x] = psum;
    __syncthreads();
    for (int off = SCAN_B / 2; off > 0; off >>= 1) {
        if (threadIdx.x < off) red[threadIdx.x] += red[threadIdx.x + off];
        __syncthreads();
    }
    int base = red[0];
    int i = blockIdx.x * SCAN_B + threadIdx.x;
    if (i < n) offsets[i] += base;
    if (blockIdx.x == 0 && threadIdx.x == 0) offsets[n] = n_edges;
}

// ---------- K4: CSR fill — NO atomics, pure dataflow scatter ----------
__global__ __launch_bounds__(256) void fill_kernel(const int* __restrict__ ei,
                                                   const float* __restrict__ ea,
                                                   const int* __restrict__ offs,
                                                   const int* __restrict__ rank,
                                                   int2* __restrict__ csr,
                                                   int n_edges) {
    int e = blockIdx.x * blockDim.x + threadIdx.x;
    if (e >= n_edges) return;
    int dst = ei[n_edges + e];
    int pos = offs[dst] + rank[e];
    long long v = ((long long)__float_as_int(ea[e]) << 32) | (unsigned)ei[e];
    __builtin_nontemporal_store(v, (long long*)(csr + pos));
}

// ---------- K5: gather, one wave per node, lane = dim, 8-wide edge ILP ------
__global__ __launch_bounds__(256) void gather_kernel(const int* __restrict__ offsets,
                                                     const int2* __restrict__ csr,
                                                     const bf16* __restrict__ xt,
                                                     const float* __restrict__ ewW,
                                                     const float* __restrict__ ewb,
                                                     const float* __restrict__ bias,
                                                     float* __restrict__ out,
                                                     int n_nodes) {
    const int d = threadIdx.x & 63;
    const int node = (blockIdx.x * blockDim.x + threadIdx.x) >> 6;
    if (node >= n_nodes) return;

    const float nwd = -ewW[d];     // negated: sigmoid arg folded into one fma
    const float nbd = -ewb[d];
    const int start = offsets[node];
    const int end = offsets[node + 1];

    float acc = 0.f;
    int k = start;
    for (; k + 8 <= end; k += 8) {
        long long q[8];
        float xv[8];
#pragma unroll
        for (int j = 0; j < 8; ++j)
            q[j] = __builtin_nontemporal_load((const long long*)(csr + k + j));
#pragma unroll
        for (int j = 0; j < 8; ++j) {
            unsigned off = ((unsigned)(int)(unsigned)q[j] << 6) + d;   // 32-bit offset
            xv[j] = __bfloat162float(xt[off]);
        }
#pragma unroll
        for (int j = 0; j < 8; ++j) {
            float a = __int_as_float((int)(q[j] >> 32));
            acc = fmaf(xv[j], fsig(a, nwd, nbd), acc);
        }
    }
    for (; k + 4 <= end; k += 4) {
        long long q0 = __builtin_nontemporal_load((const long long*)(csr + k + 0));
        long long q1 = __builtin_nontemporal_load((const long long*)(csr + k + 1));
        long long q2 = __builtin_nontemporal_load((const long long*)(csr + k + 2));
        long long q3 = __builtin_nontemporal_load((const long long*)(csr + k + 3));
        float x0 = __bfloat162float(xt[(((unsigned)(int)(unsigned)q0) << 6) + d]);
        float x1 = __bfloat162float(xt[(((unsigned)(int)(unsigned)q1) << 6) + d]);
        float x2 = __bfloat162float(xt[(((unsigned)(int)(unsigned)q2) << 6) + d]);
        float x3 = __bfloat162float(xt[(((unsigned)(int)(unsigned)q3) << 6) + d]);
        acc = fmaf(x0, fsig(__int_as_float((int)(q0 >> 32)), nwd, nbd), acc);
        acc = fmaf(x1, fsig(__int_as_float((int)(q1 >> 32)), nwd, nbd), acc);
        acc = fmaf(x2, fsig(__int_as_float((int)(q2 >> 32)), nwd, nbd), acc);
        acc = fmaf(x3, fsig(__int_as_float((int)(q3 >> 32)), nwd, nbd), acc);
    }
    for (; k < end; ++k) {
        long long q = __builtin_nontemporal_load((const long long*)(csr + k));
        float xv = __bfloat162float(xt[(((unsigned)(int)(unsigned)q) << 6) + d]);
        acc = fmaf(xv, fsig(__int_as_float((int)(q >> 32)), nwd, nbd), acc);
    }
    float r = acc + bias[d];
    __builtin_nontemporal_store(r, out + (size_t)node * 64 + d);
}

// ---------- fallback (atomic scatter) ----------
__global__ __launch_bounds__(256) void init_out_kernel(float* __restrict__ out,
                                                       const float* __restrict__ bias,
                                                       int n_f4) {
    int i = blockIdx.x * blockDim.x + threadIdx.x;
    if (i >= n_f4) return;
    float4 b4 = reinterpret_cast<const float4*>(bias)[i & 15];
    reinterpret_cast<float4*>(out)[i] = b4;
}

__global__ __launch_bounds__(256) void edge_atomic_kernel(const int* __restrict__ ei,
                                                          const float* __restrict__ ea,
                                                          const bf16* __restrict__ xt,
                                                          const float* __restrict__ ewW,
                                                          const float* __restrict__ ewb,
                                                          float* __restrict__ out,
                                                          int n_edges) {
    const int gid = blockIdx.x * blockDim.x + threadIdx.x;
    const int d0 = (gid & 15) * 4;
    int e = gid >> 4;
    const int estride = (gridDim.x * blockDim.x) >> 4;
    for (; e < n_edges; e += estride) {
        const int src = ei[e];
        const int dst = ei[n_edges + e];
        const float a = ea[e];
        float xv0 = __bfloat162float(xt[(size_t)src * 64 + d0 + 0]);
        float xv1 = __bfloat162float(xt[(size_t)src * 64 + d0 + 1]);
        float xv2 = __bfloat162float(xt[(size_t)src * 64 + d0 + 2]);
        float xv3 = __bfloat162float(xt[(size_t)src * 64 + d0 + 3]);
        float w0 = fsig(a, -ewW[d0 + 0], -ewb[d0 + 0]);
        float w1 = fsig(a, -ewW[d0 + 1], -ewb[d0 + 1]);
        float w2 = fsig(a, -ewW[d0 + 2], -ewb[d0 + 2]);
        float w3 = fsig(a, -ewW[d0 + 3], -ewb[d0 + 3]);
        float* op = out + (size_t)dst * 64 + d0;
        unsafeAtomicAdd(op + 0, xv0 * w0);
        unsafeAtomicAdd(op + 1, xv1 * w1);
        unsafeAtomicAdd(op + 2, xv2 * w2);
        unsafeAtomicAdd(op + 3, xv3 * w3);
    }
}

extern "C" void kernel_launch(void* const* d_in, const int* in_sizes, int n_in,
                              void* d_out, int out_size, void* d_ws, size_t ws_size,
                              hipStream_t stream) {
    const float* x      = (const float*)d_in[0];
    const int*   ei     = (const int*)d_in[1];
    const float* ea     = (const float*)d_in[2];
    const float* weight = (const float*)d_in[3];
    const float* ewW    = (const float*)d_in[4];
    const float* ewb    = (const float*)d_in[5];
    const float* bias   = (const float*)d_in[6];
    float* out = (float*)d_out;

    const int n_nodes = in_sizes[0] / D;   // 100000
    const int n_edges = in_sizes[2];       // 1600000

    // workspace layout
    char* ws = (char*)d_ws;
    const size_t xt_bytes   = (size_t)n_nodes * D * sizeof(bf16);      // 12.8 MB
    const size_t off_off    = (xt_bytes + 7) & ~(size_t)7;
    const size_t off_bytes  = ((size_t)n_nodes + 4) * sizeof(int);
    const size_t part_off   = off_off + off_bytes;
    const size_t part_bytes = 512 * sizeof(int);
    const size_t rank_off   = part_off + part_bytes;
    const size_t rank_bytes = (size_t)n_edges * sizeof(int);           // 6.4 MB
    size_t csr_off          = (rank_off + rank_bytes + 7) & ~(size_t)7;
    const size_t csr_bytes  = (size_t)n_edges * sizeof(int2);          // 12.8 MB
    const size_t need       = csr_off + csr_bytes;                     // ~32.5 MB

    bf16* xt   = (bf16*)(ws);
    int*  offs = (int*)(ws + off_off);
    int*  parts= (int*)(ws + part_off);
    int*  rank = (int*)(ws + rank_off);
    int2* csr  = (int2*)(ws + csr_off);

    const bool have_ws = (ws_size >= need);
    const int gemm_grid = (n_nodes + 63) / 64;   // 1563

    if (have_ws) {
        hipMemsetAsync(offs, 0, off_bytes, stream);
        hist_kernel<<<2048, 256, 0, stream>>>(ei, offs, rank, n_edges);
        gemm_mfma_kernel<<<gemm_grid, 256, 0, stream>>>(x, weight, xt, n_nodes);

        const int nscan_blocks = (n_nodes + SCAN_B - 1) / SCAN_B;   // 391
        scan1_kernel<<<nscan_blocks, SCAN_B, 0, stream>>>(offs, offs, parts, n_nodes);
        scan23_kernel<<<nscan_blocks, SCAN_B, 0, stream>>>(offs, parts, n_nodes, n_edges);
        fill_kernel<<<(n_edges + 255) / 256, 256, 0, stream>>>(ei, ea, offs, rank, csr, n_edges);
        gather_kernel<<<(n_nodes * 64 + 255) / 256, 256, 0, stream>>>(offs, csr, xt, ewW, ewb,
                                                                      bias, out, n_nodes);
    } else {
        gemm_mfma_kernel<<<gemm_grid, 256, 0, stream>>>(x, weight, xt, n_nodes);
        int n_f4 = n_nodes * (D / 4);
        init_out_kernel<<<(n_f4 + 255) / 256, 256, 0, stream>>>(out, bias, n_f4);
        edge_atomic_kernel<<<4096, 256, 0, stream>>>(ei, ea, xt, ewW, ewb, out, n_edges);
    }
}

// Round 11
// 189.750 us; speedup vs baseline: 2.4962x; 1.1281x over previous
//
#include <hip/hip_runtime.h>
#include <hip/hip_bf16.h>
#include <math.h>

#define D 64
#define SCAN_B 256

typedef __hip_bfloat16 bf16;
typedef __attribute__((ext_vector_type(8))) short bf16x8;   // 8 bf16 (4 VGPRs)
typedef __attribute__((ext_vector_type(4))) float f32x4;
typedef __attribute__((ext_vector_type(2))) float f32x2;    // native vec for nt-store

static __device__ __forceinline__ short f2bf(float f) {
    unsigned u = __float_as_uint(f);
    u = (u + 0x7FFFu + ((u >> 16) & 1u)) >> 16;   // RNE
    return (short)u;
}
static __device__ __forceinline__ float bf2f(unsigned short h) {
    return __uint_as_float(((unsigned)h) << 16);
}
// fast sigmoid: rcp approx instead of precise-division fixup sequence
static __device__ __forceinline__ float fsig(float a, float nwd, float nbd) {
    float e = __expf(fmaf(a, nwd, nbd));          // exp(-(a*wd+bd))
    return __builtin_amdgcn_rcpf(1.f + e);
}

// ---------- K1: fused dst-histogram (rank capture) + xt = x @ W via MFMA ----
// hist atomics (independent of GEMM data) issue first; their latency hides
// under the MFMA phase via the other waves. MFMA: bf16 in, fp32 accum.
__global__ __launch_bounds__(256) void gemm_hist_kernel(const float* __restrict__ x,
                                                        const float* __restrict__ W,
                                                        const int* __restrict__ ei,
                                                        bf16* __restrict__ xt,
                                                        int* __restrict__ counts,
                                                        int* __restrict__ rank,
                                                        int n_nodes, int n_edges) {
    __shared__ float Ws[64 * 64];
    {
        const float4* src = reinterpret_cast<const float4*>(W);
        float4* dstp = reinterpret_cast<float4*>(Ws);
        for (int i = threadIdx.x; i < 1024; i += 256) dstp[i] = src[i];
    }

    const int gid = blockIdx.x * blockDim.x + threadIdx.x;
    const int nth = gridDim.x * blockDim.x;

    // phase A: histogram of dst with rank capture
    for (int e = gid; e < n_edges; e += nth) {
        int dst = ei[n_edges + e];
        rank[e] = atomicAdd(&counts[dst], 1);
    }

    __syncthreads();   // Ws ready

    // phase B: MFMA GEMM. wave -> 16 rows x 64 cols.
    const int lane  = threadIdx.x & 63;
    const int wv    = threadIdx.x >> 6;
    const int m0    = blockIdx.x * 64 + wv * 16;
    const int half  = lane >> 4;
    const int idx16 = lane & 15;
    const int k0    = half * 8;

    bf16x8 bfrag[4][2];
#pragma unroll
    for (int t = 0; t < 4; ++t) {
#pragma unroll
        for (int h = 0; h < 2; ++h) {
            bf16x8 f;
#pragma unroll
            for (int j = 0; j < 8; ++j)
                f[j] = f2bf(Ws[(h * 32 + k0 + j) * 64 + t * 16 + idx16]);
            bfrag[t][h] = f;
        }
    }

    const int am = m0 + idx16;
    const bool valid = (am < n_nodes);
    const float* arow = x + (size_t)(valid ? am : 0) * 64;

    f32x4 acc[4] = {{0.f, 0.f, 0.f, 0.f}, {0.f, 0.f, 0.f, 0.f},
                    {0.f, 0.f, 0.f, 0.f}, {0.f, 0.f, 0.f, 0.f}};

#pragma unroll
    for (int h = 0; h < 2; ++h) {
        bf16x8 afrag = {0, 0, 0, 0, 0, 0, 0, 0};
        if (valid) {
            float4 p0 = *reinterpret_cast<const float4*>(arow + h * 32 + k0);
            float4 p1 = *reinterpret_cast<const float4*>(arow + h * 32 + k0 + 4);
            afrag[0] = f2bf(p0.x); afrag[1] = f2bf(p0.y);
            afrag[2] = f2bf(p0.z); afrag[3] = f2bf(p0.w);
            afrag[4] = f2bf(p1.x); afrag[5] = f2bf(p1.y);
            afrag[6] = f2bf(p1.z); afrag[7] = f2bf(p1.w);
        }
#pragma unroll
        for (int t = 0; t < 4; ++t)
            acc[t] = __builtin_amdgcn_mfma_f32_16x16x32_bf16(afrag, bfrag[t][h],
                                                             acc[t], 0, 0, 0);
    }

    const int srow0 = m0 + half * 4;
#pragma unroll
    for (int r = 0; r < 4; ++r) {
        int row = srow0 + r;
        if (row < n_nodes) {
#pragma unroll
            for (int t = 0; t < 4; ++t)
                xt[(size_t)row * 64 + t * 16 + idx16] = __float2bfloat16(acc[t][r]);
        }
    }
}

// ---------- K2: block scan (exclusive) + block totals ----------
__global__ __launch_bounds__(SCAN_B) void scan1_kernel(const int* __restrict__ c,
                                                       int* __restrict__ excl,
                                                       int* __restrict__ partials,
                                                       int n) {
    __shared__ int s[SCAN_B];
    int i = blockIdx.x * SCAN_B + threadIdx.x;
    int v = (i < n) ? c[i] : 0;
    s[threadIdx.x] = v;
    __syncthreads();
    for (int off = 1; off < SCAN_B; off <<= 1) {
        int t = (threadIdx.x >= off) ? s[threadIdx.x - off] : 0;
        __syncthreads();
        s[threadIdx.x] += t;
        __syncthreads();
    }
    if (i < n) excl[i] = s[threadIdx.x] - v;
    if (threadIdx.x == SCAN_B - 1) partials[blockIdx.x] = s[SCAN_B - 1];
}

// ---------- K3: apply partials prefix ----------
__global__ __launch_bounds__(SCAN_B) void scan23_kernel(int* __restrict__ offsets,
                                                        const int* __restrict__ partials,
                                                        int n, int n_edges) {
    __shared__ int red[SCAN_B];
    int psum = 0;
    for (int i = threadIdx.x; i < blockIdx.x; i += SCAN_B) psum += partials[i];
    red[threadIdx.x] = psum;
    __syncthreads();
    for (int off = SCAN_B / 2; off > 0; off >>= 1) {
        if (threadIdx.x < off) red[threadIdx.x] += red[threadIdx.x + off];
        __syncthreads();
    }
    int base = red[0];
    int i = blockIdx.x * SCAN_B + threadIdx.x;
    if (i < n) offsets[i] += base;
    if (blockIdx.x == 0 && threadIdx.x == 0) offsets[n] = n_edges;
}

// ---------- K4: CSR fill — NO atomics, pure dataflow scatter ----------
__global__ __launch_bounds__(256) void fill_kernel(const int* __restrict__ ei,
                                                   const float* __restrict__ ea,
                                                   const int* __restrict__ offs,
                                                   const int* __restrict__ rank,
                                                   int2* __restrict__ csr,
                                                   int n_edges) {
    int e = blockIdx.x * blockDim.x + threadIdx.x;
    if (e >= n_edges) return;
    int dst = ei[n_edges + e];
    int pos = offs[dst] + rank[e];
    long long v = ((long long)__float_as_int(ea[e]) << 32) | (unsigned)ei[e];
    __builtin_nontemporal_store(v, (long long*)(csr + pos));
}

// ---------- K5: gather — 2 nodes/wave, 2 dims/lane (ushort2 row loads) -----
__global__ __launch_bounds__(256) void gather_kernel(const int* __restrict__ offsets,
                                                     const int2* __restrict__ csr,
                                                     const bf16* __restrict__ xt,
                                                     const float* __restrict__ ewW,
                                                     const float* __restrict__ ewb,
                                                     const float* __restrict__ bias,
                                                     float* __restrict__ out,
                                                     int n_nodes) {
    const int lane  = threadIdx.x & 63;
    const int halfw = lane >> 5;                     // which node of the pair
    const int l     = lane & 31;
    const int d0    = l * 2;                         // dims d0, d0+1
    const int wavei = (blockIdx.x * blockDim.x + threadIdx.x) >> 6;
    const int node  = wavei * 2 + halfw;
    if (node >= n_nodes) return;

    const float2 wv = *reinterpret_cast<const float2*>(ewW + d0);
    const float2 bv = *reinterpret_cast<const float2*>(ewb + d0);
    const float nw0 = -wv.x, nb0 = -bv.x;
    const float nw1 = -wv.y, nb1 = -bv.y;

    const int start = offsets[node];
    const int end   = offsets[node + 1];

    float acc0 = 0.f, acc1 = 0.f;
    int k = start;
    for (; k + 8 <= end; k += 8) {
        long long q[8];
        ushort2 rv[8];
#pragma unroll
        for (int j = 0; j < 8; ++j)
            q[j] = __builtin_nontemporal_load((const long long*)(csr + k + j));
#pragma unroll
        for (int j = 0; j < 8; ++j) {
            unsigned off = (((unsigned)(int)(unsigned)q[j]) << 6) + d0;
            rv[j] = *reinterpret_cast<const ushort2*>(xt + off);
        }
#pragma unroll
        for (int j = 0; j < 8; ++j) {
            float a = __int_as_float((int)(q[j] >> 32));
            acc0 = fmaf(bf2f(rv[j].x), fsig(a, nw0, nb0), acc0);
            acc1 = fmaf(bf2f(rv[j].y), fsig(a, nw1, nb1), acc1);
        }
    }
    for (; k + 4 <= end; k += 4) {
        long long q[4];
        ushort2 rv[4];
#pragma unroll
        for (int j = 0; j < 4; ++j)
            q[j] = __builtin_nontemporal_load((const long long*)(csr + k + j));
#pragma unroll
        for (int j = 0; j < 4; ++j) {
            unsigned off = (((unsigned)(int)(unsigned)q[j]) << 6) + d0;
            rv[j] = *reinterpret_cast<const ushort2*>(xt + off);
        }
#pragma unroll
        for (int j = 0; j < 4; ++j) {
            float a = __int_as_float((int)(q[j] >> 32));
            acc0 = fmaf(bf2f(rv[j].x), fsig(a, nw0, nb0), acc0);
            acc1 = fmaf(bf2f(rv[j].y), fsig(a, nw1, nb1), acc1);
        }
    }
    for (; k < end; ++k) {
        long long q = __builtin_nontemporal_load((const long long*)(csr + k));
        unsigned off = (((unsigned)(int)(unsigned)q) << 6) + d0;
        ushort2 rv = *reinterpret_cast<const ushort2*>(xt + off);
        float a = __int_as_float((int)(q >> 32));
        acc0 = fmaf(bf2f(rv.x), fsig(a, nw0, nb0), acc0);
        acc1 = fmaf(bf2f(rv.y), fsig(a, nw1, nb1), acc1);
    }
    f32x2 o;
    o.x = acc0 + bias[d0];
    o.y = acc1 + bias[d0 + 1];
    __builtin_nontemporal_store(o, reinterpret_cast<f32x2*>(out + (size_t)node * 64 + d0));
}

// ---------- fallback (atomic scatter) ----------
__global__ __launch_bounds__(256) void init_out_kernel(float* __restrict__ out,
                                                       const float* __restrict__ bias,
                                                       int n_f4) {
    int i = blockIdx.x * blockDim.x + threadIdx.x;
    if (i >= n_f4) return;
    float4 b4 = reinterpret_cast<const float4*>(bias)[i & 15];
    reinterpret_cast<float4*>(out)[i] = b4;
}

__global__ __launch_bounds__(256) void edge_atomic_kernel(const int* __restrict__ ei,
                                                          const float* __restrict__ ea,
                                                          const bf16* __restrict__ xt,
                                                          const float* __restrict__ ewW,
                                                          const float* __restrict__ ewb,
                                                          float* __restrict__ out,
                                                          int n_edges) {
    const int gid = blockIdx.x * blockDim.x + threadIdx.x;
    const int d0 = (gid & 15) * 4;
    int e = gid >> 4;
    const int estride = (gridDim.x * blockDim.x) >> 4;
    for (; e < n_edges; e += estride) {
        const int src = ei[e];
        const int dst = ei[n_edges + e];
        const float a = ea[e];
        float xv0 = __bfloat162float(xt[(size_t)src * 64 + d0 + 0]);
        float xv1 = __bfloat162float(xt[(size_t)src * 64 + d0 + 1]);
        float xv2 = __bfloat162float(xt[(size_t)src * 64 + d0 + 2]);
        float xv3 = __bfloat162float(xt[(size_t)src * 64 + d0 + 3]);
        float w0 = fsig(a, -ewW[d0 + 0], -ewb[d0 + 0]);
        float w1 = fsig(a, -ewW[d0 + 1], -ewb[d0 + 1]);
        float w2 = fsig(a, -ewW[d0 + 2], -ewb[d0 + 2]);
        float w3 = fsig(a, -ewW[d0 + 3], -ewb[d0 + 3]);
        float* op = out + (size_t)dst * 64 + d0;
        unsafeAtomicAdd(op + 0, xv0 * w0);
        unsafeAtomicAdd(op + 1, xv1 * w1);
        unsafeAtomicAdd(op + 2, xv2 * w2);
        unsafeAtomicAdd(op + 3, xv3 * w3);
    }
}

extern "C" void kernel_launch(void* const* d_in, const int* in_sizes, int n_in,
                              void* d_out, int out_size, void* d_ws, size_t ws_size,
                              hipStream_t stream) {
    const float* x      = (const float*)d_in[0];
    const int*   ei     = (const int*)d_in[1];
    const float* ea     = (const float*)d_in[2];
    const float* weight = (const float*)d_in[3];
    const float* ewW    = (const float*)d_in[4];
    const float* ewb    = (const float*)d_in[5];
    const float* bias   = (const float*)d_in[6];
    float* out = (float*)d_out;

    const int n_nodes = in_sizes[0] / D;   // 100000
    const int n_edges = in_sizes[2];       // 1600000

    // workspace layout
    char* ws = (char*)d_ws;
    const size_t xt_bytes   = (size_t)n_nodes * D * sizeof(bf16);      // 12.8 MB
    const size_t off_off    = (xt_bytes + 7) & ~(size_t)7;
    const size_t off_bytes  = ((size_t)n_nodes + 4) * sizeof(int);
    const size_t part_off   = off_off + off_bytes;
    const size_t part_bytes = 512 * sizeof(int);
    const size_t rank_off   = part_off + part_bytes;
    const size_t rank_bytes = (size_t)n_edges * sizeof(int);           // 6.4 MB
    size_t csr_off          = (rank_off + rank_bytes + 7) & ~(size_t)7;
    const size_t csr_bytes  = (size_t)n_edges * sizeof(int2);          // 12.8 MB
    const size_t need       = csr_off + csr_bytes;                     // ~32.5 MB

    bf16* xt   = (bf16*)(ws);
    int*  offs = (int*)(ws + off_off);
    int*  parts= (int*)(ws + part_off);
    int*  rank = (int*)(ws + rank_off);
    int2* csr  = (int2*)(ws + csr_off);

    const bool have_ws = (ws_size >= need);
    const int gemm_grid = (n_nodes + 63) / 64;   // 1563

    if (have_ws) {
        (void)hipMemsetAsync(offs, 0, off_bytes, stream);
        gemm_hist_kernel<<<gemm_grid, 256, 0, stream>>>(x, weight, ei, xt, offs, rank,
                                                        n_nodes, n_edges);

        const int nscan_blocks = (n_nodes + SCAN_B - 1) / SCAN_B;   // 391
        scan1_kernel<<<nscan_blocks, SCAN_B, 0, stream>>>(offs, offs, parts, n_nodes);
        scan23_kernel<<<nscan_blocks, SCAN_B, 0, stream>>>(offs, parts, n_nodes, n_edges);
        fill_kernel<<<(n_edges + 255) / 256, 256, 0, stream>>>(ei, ea, offs, rank, csr, n_edges);

        const int n_waves = (n_nodes + 1) / 2;               // 2 nodes per wave
        const int gth = n_waves * 64;
        gather_kernel<<<(gth + 255) / 256, 256, 0, stream>>>(offs, csr, xt, ewW, ewb,
                                                             bias, out, n_nodes);
    } else {
        gemm_hist_kernel<<<gemm_grid, 256, 0, stream>>>(x, weight, ei, xt,
                                                        nullptr, nullptr, n_nodes, 0);
        int n_f4 = n_nodes * (D / 4);
        init_out_kernel<<<(n_f4 + 255) / 256, 256, 0, stream>>>(out, bias, n_f4);
        edge_atomic_kernel<<<4096, 256, 0, stream>>>(ei, ea, xt, ewW, ewb, out, n_edges);
    }
}

// Round 12
// 187.405 us; speedup vs baseline: 2.5275x; 1.0125x over previous
//
#include <hip/hip_runtime.h>
#include <hip/hip_bf16.h>
#include <math.h>

#define D 64
#define SCAN_B 256

typedef __hip_bfloat16 bf16;
typedef __attribute__((ext_vector_type(8))) short bf16x8;   // 8 bf16 (4 VGPRs)
typedef __attribute__((ext_vector_type(4))) float f32x4;

static __device__ __forceinline__ short f2bf(float f) {
    unsigned u = __float_as_uint(f);
    u = (u + 0x7FFFu + ((u >> 16) & 1u)) >> 16;   // RNE
    return (short)u;
}
static __device__ __forceinline__ float bf2f(unsigned short h) {
    return __uint_as_float(((unsigned)h) << 16);
}
// fast sigmoid: rcp approx instead of precise-division fixup sequence
static __device__ __forceinline__ float fsig(float a, float nwd, float nbd) {
    float e = __expf(fmaf(a, nwd, nbd));          // exp(-(a*wd+bd))
    return __builtin_amdgcn_rcpf(1.f + e);
}

// ---------- K1: role-split block fusion: hist blocks || MFMA-GEMM blocks ----
// No __syncthreads coupling between roles: atomic-return latency of hist
// blocks hides under co-resident gemm blocks' MFMA/load work.
__global__ __launch_bounds__(256) void gemm_hist_kernel(const float* __restrict__ x,
                                                        const float* __restrict__ W,
                                                        const int* __restrict__ ei,
                                                        bf16* __restrict__ xt,
                                                        int* __restrict__ counts,
                                                        int* __restrict__ rank,
                                                        int n_nodes, int n_edges,
                                                        int hist_blocks) {
    __shared__ float Ws[64 * 64];

    if ((int)blockIdx.x < hist_blocks) {
        // ---- role A: dst-histogram with rank capture ----
        const int gid = blockIdx.x * blockDim.x + threadIdx.x;
        const int nth = hist_blocks * blockDim.x;
        for (int e = gid; e < n_edges; e += nth) {
            int dst = ei[n_edges + e];
            rank[e] = atomicAdd(&counts[dst], 1);
        }
        return;
    }

    // ---- role B: MFMA GEMM, wave -> 16 rows x 64 cols ----
    const int bid = blockIdx.x - hist_blocks;
    {
        const float4* src = reinterpret_cast<const float4*>(W);
        float4* dstp = reinterpret_cast<float4*>(Ws);
        for (int i = threadIdx.x; i < 1024; i += 256) dstp[i] = src[i];
    }
    __syncthreads();

    const int lane  = threadIdx.x & 63;
    const int wv    = threadIdx.x >> 6;
    const int m0    = bid * 64 + wv * 16;
    const int half  = lane >> 4;
    const int idx16 = lane & 15;
    const int k0    = half * 8;

    bf16x8 bfrag[4][2];
#pragma unroll
    for (int t = 0; t < 4; ++t) {
#pragma unroll
        for (int h = 0; h < 2; ++h) {
            bf16x8 f;
#pragma unroll
            for (int j = 0; j < 8; ++j)
                f[j] = f2bf(Ws[(h * 32 + k0 + j) * 64 + t * 16 + idx16]);
            bfrag[t][h] = f;
        }
    }

    const int am = m0 + idx16;
    const bool valid = (am < n_nodes);
    const float* arow = x + (size_t)(valid ? am : 0) * 64;

    f32x4 acc[4] = {{0.f, 0.f, 0.f, 0.f}, {0.f, 0.f, 0.f, 0.f},
                    {0.f, 0.f, 0.f, 0.f}, {0.f, 0.f, 0.f, 0.f}};

#pragma unroll
    for (int h = 0; h < 2; ++h) {
        bf16x8 afrag = {0, 0, 0, 0, 0, 0, 0, 0};
        if (valid) {
            float4 p0 = *reinterpret_cast<const float4*>(arow + h * 32 + k0);
            float4 p1 = *reinterpret_cast<const float4*>(arow + h * 32 + k0 + 4);
            afrag[0] = f2bf(p0.x); afrag[1] = f2bf(p0.y);
            afrag[2] = f2bf(p0.z); afrag[3] = f2bf(p0.w);
            afrag[4] = f2bf(p1.x); afrag[5] = f2bf(p1.y);
            afrag[6] = f2bf(p1.z); afrag[7] = f2bf(p1.w);
        }
#pragma unroll
        for (int t = 0; t < 4; ++t)
            acc[t] = __builtin_amdgcn_mfma_f32_16x16x32_bf16(afrag, bfrag[t][h],
                                                             acc[t], 0, 0, 0);
    }

    const int srow0 = m0 + half * 4;
#pragma unroll
    for (int r = 0; r < 4; ++r) {
        int row = srow0 + r;
        if (row < n_nodes) {
#pragma unroll
            for (int t = 0; t < 4; ++t)
                xt[(size_t)row * 64 + t * 16 + idx16] = __float2bfloat16(acc[t][r]);
        }
    }
}

// ---------- K2: block scan (exclusive) + block totals ----------
__global__ __launch_bounds__(SCAN_B) void scan1_kernel(const int* __restrict__ c,
                                                       int* __restrict__ excl,
                                                       int* __restrict__ partials,
                                                       int n) {
    __shared__ int s[SCAN_B];
    int i = blockIdx.x * SCAN_B + threadIdx.x;
    int v = (i < n) ? c[i] : 0;
    s[threadIdx.x] = v;
    __syncthreads();
    for (int off = 1; off < SCAN_B; off <<= 1) {
        int t = (threadIdx.x >= off) ? s[threadIdx.x - off] : 0;
        __syncthreads();
        s[threadIdx.x] += t;
        __syncthreads();
    }
    if (i < n) excl[i] = s[threadIdx.x] - v;
    if (threadIdx.x == SCAN_B - 1) partials[blockIdx.x] = s[SCAN_B - 1];
}

// ---------- K3: apply partials prefix ----------
__global__ __launch_bounds__(SCAN_B) void scan23_kernel(int* __restrict__ offsets,
                                                        const int* __restrict__ partials,
                                                        int n, int n_edges) {
    __shared__ int red[SCAN_B];
    int psum = 0;
    for (int i = threadIdx.x; i < blockIdx.x; i += SCAN_B) psum += partials[i];
    red[threadIdx.x] = psum;
    __syncthreads();
    for (int off = SCAN_B / 2; off > 0; off >>= 1) {
        if (threadIdx.x < off) red[threadIdx.x] += red[threadIdx.x + off];
        __syncthreads();
    }
    int base = red[0];
    int i = blockIdx.x * SCAN_B + threadIdx.x;
    if (i < n) offsets[i] += base;
    if (blockIdx.x == 0 && threadIdx.x == 0) offsets[n] = n_edges;
}

// ---------- K4: CSR fill — NO atomics, pure dataflow scatter ----------
__global__ __launch_bounds__(256) void fill_kernel(const int* __restrict__ ei,
                                                   const float* __restrict__ ea,
                                                   const int* __restrict__ offs,
                                                   const int* __restrict__ rank,
                                                   int2* __restrict__ csr,
                                                   int n_edges) {
    int e = blockIdx.x * blockDim.x + threadIdx.x;
    if (e >= n_edges) return;
    int dst = ei[n_edges + e];
    int pos = offs[dst] + rank[e];
    long long v = ((long long)__float_as_int(ea[e]) << 32) | (unsigned)ei[e];
    __builtin_nontemporal_store(v, (long long*)(csr + pos));
}

// ---------- K5: gather — 4 nodes/wave, 4 dims/lane (ushort4 row loads) -----
__global__ __launch_bounds__(256) void gather_kernel(const int* __restrict__ offsets,
                                                     const int2* __restrict__ csr,
                                                     const bf16* __restrict__ xt,
                                                     const float* __restrict__ ewW,
                                                     const float* __restrict__ ewb,
                                                     const float* __restrict__ bias,
                                                     float* __restrict__ out,
                                                     int n_nodes) {
    const int lane  = threadIdx.x & 63;
    const int sub   = lane >> 4;                     // node index within wave
    const int l     = lane & 15;
    const int d0    = l * 4;                         // dims d0..d0+3
    const int wavei = (blockIdx.x * blockDim.x + threadIdx.x) >> 6;
    const int node  = wavei * 4 + sub;
    if (node >= n_nodes) return;

    const float4 wv4 = *reinterpret_cast<const float4*>(ewW + d0);
    const float4 bv4 = *reinterpret_cast<const float4*>(ewb + d0);
    const float nw0 = -wv4.x, nw1 = -wv4.y, nw2 = -wv4.z, nw3 = -wv4.w;
    const float nb0 = -bv4.x, nb1 = -bv4.y, nb2 = -bv4.z, nb3 = -bv4.w;

    const int start = offsets[node];
    const int end   = offsets[node + 1];

    float acc0 = 0.f, acc1 = 0.f, acc2 = 0.f, acc3 = 0.f;
    int k = start;
    for (; k + 8 <= end; k += 8) {
        long long q[8];
        ushort4 rv[8];
#pragma unroll
        for (int j = 0; j < 8; ++j)
            q[j] = __builtin_nontemporal_load((const long long*)(csr + k + j));
#pragma unroll
        for (int j = 0; j < 8; ++j) {
            unsigned off = (((unsigned)(int)(unsigned)q[j]) << 6) + d0;
            rv[j] = *reinterpret_cast<const ushort4*>(xt + off);
        }
#pragma unroll
        for (int j = 0; j < 8; ++j) {
            float a = __int_as_float((int)(q[j] >> 32));
            acc0 = fmaf(bf2f(rv[j].x), fsig(a, nw0, nb0), acc0);
            acc1 = fmaf(bf2f(rv[j].y), fsig(a, nw1, nb1), acc1);
            acc2 = fmaf(bf2f(rv[j].z), fsig(a, nw2, nb2), acc2);
            acc3 = fmaf(bf2f(rv[j].w), fsig(a, nw3, nb3), acc3);
        }
    }
    for (; k + 4 <= end; k += 4) {
        long long q[4];
        ushort4 rv[4];
#pragma unroll
        for (int j = 0; j < 4; ++j)
            q[j] = __builtin_nontemporal_load((const long long*)(csr + k + j));
#pragma unroll
        for (int j = 0; j < 4; ++j) {
            unsigned off = (((unsigned)(int)(unsigned)q[j]) << 6) + d0;
            rv[j] = *reinterpret_cast<const ushort4*>(xt + off);
        }
#pragma unroll
        for (int j = 0; j < 4; ++j) {
            float a = __int_as_float((int)(q[j] >> 32));
            acc0 = fmaf(bf2f(rv[j].x), fsig(a, nw0, nb0), acc0);
            acc1 = fmaf(bf2f(rv[j].y), fsig(a, nw1, nb1), acc1);
            acc2 = fmaf(bf2f(rv[j].z), fsig(a, nw2, nb2), acc2);
            acc3 = fmaf(bf2f(rv[j].w), fsig(a, nw3, nb3), acc3);
        }
    }
    for (; k < end; ++k) {
        long long q = __builtin_nontemporal_load((const long long*)(csr + k));
        unsigned off = (((unsigned)(int)(unsigned)q) << 6) + d0;
        ushort4 rv = *reinterpret_cast<const ushort4*>(xt + off);
        float a = __int_as_float((int)(q >> 32));
        acc0 = fmaf(bf2f(rv.x), fsig(a, nw0, nb0), acc0);
        acc1 = fmaf(bf2f(rv.y), fsig(a, nw1, nb1), acc1);
        acc2 = fmaf(bf2f(rv.z), fsig(a, nw2, nb2), acc2);
        acc3 = fmaf(bf2f(rv.w), fsig(a, nw3, nb3), acc3);
    }
    f32x4 o;
    o.x = acc0 + bias[d0 + 0];
    o.y = acc1 + bias[d0 + 1];
    o.z = acc2 + bias[d0 + 2];
    o.w = acc3 + bias[d0 + 3];
    __builtin_nontemporal_store(o, reinterpret_cast<f32x4*>(out + (size_t)node * 64 + d0));
}

// ---------- fallback (atomic scatter) ----------
__global__ __launch_bounds__(256) void init_out_kernel(float* __restrict__ out,
                                                       const float* __restrict__ bias,
                                                       int n_f4) {
    int i = blockIdx.x * blockDim.x + threadIdx.x;
    if (i >= n_f4) return;
    float4 b4 = reinterpret_cast<const float4*>(bias)[i & 15];
    reinterpret_cast<float4*>(out)[i] = b4;
}

__global__ __launch_bounds__(256) void edge_atomic_kernel(const int* __restrict__ ei,
                                                          const float* __restrict__ ea,
                                                          const bf16* __restrict__ xt,
                                                          const float* __restrict__ ewW,
                                                          const float* __restrict__ ewb,
                                                          float* __restrict__ out,
                                                          int n_edges) {
    const int gid = blockIdx.x * blockDim.x + threadIdx.x;
    const int d0 = (gid & 15) * 4;
    int e = gid >> 4;
    const int estride = (gridDim.x * blockDim.x) >> 4;
    for (; e < n_edges; e += estride) {
        const int src = ei[e];
        const int dst = ei[n_edges + e];
        const float a = ea[e];
        float xv0 = __bfloat162float(xt[(size_t)src * 64 + d0 + 0]);
        float xv1 = __bfloat162float(xt[(size_t)src * 64 + d0 + 1]);
        float xv2 = __bfloat162float(xt[(size_t)src * 64 + d0 + 2]);
        float xv3 = __bfloat162float(xt[(size_t)src * 64 + d0 + 3]);
        float w0 = fsig(a, -ewW[d0 + 0], -ewb[d0 + 0]);
        float w1 = fsig(a, -ewW[d0 + 1], -ewb[d0 + 1]);
        float w2 = fsig(a, -ewW[d0 + 2], -ewb[d0 + 2]);
        float w3 = fsig(a, -ewW[d0 + 3], -ewb[d0 + 3]);
        float* op = out + (size_t)dst * 64 + d0;
        unsafeAtomicAdd(op + 0, xv0 * w0);
        unsafeAtomicAdd(op + 1, xv1 * w1);
        unsafeAtomicAdd(op + 2, xv2 * w2);
        unsafeAtomicAdd(op + 3, xv3 * w3);
    }
}

extern "C" void kernel_launch(void* const* d_in, const int* in_sizes, int n_in,
                              void* d_out, int out_size, void* d_ws, size_t ws_size,
                              hipStream_t stream) {
    const float* x      = (const float*)d_in[0];
    const int*   ei     = (const int*)d_in[1];
    const float* ea     = (const float*)d_in[2];
    const float* weight = (const float*)d_in[3];
    const float* ewW    = (const float*)d_in[4];
    const float* ewb    = (const float*)d_in[5];
    const float* bias   = (const float*)d_in[6];
    float* out = (float*)d_out;

    const int n_nodes = in_sizes[0] / D;   // 100000
    const int n_edges = in_sizes[2];       // 1600000

    // workspace layout
    char* ws = (char*)d_ws;
    const size_t xt_bytes   = (size_t)n_nodes * D * sizeof(bf16);      // 12.8 MB
    const size_t off_off    = (xt_bytes + 7) & ~(size_t)7;
    const size_t off_bytes  = ((size_t)n_nodes + 4) * sizeof(int);
    const size_t part_off   = off_off + off_bytes;
    const size_t part_bytes = 512 * sizeof(int);
    const size_t rank_off   = part_off + part_bytes;
    const size_t rank_bytes = (size_t)n_edges * sizeof(int);           // 6.4 MB
    size_t csr_off          = (rank_off + rank_bytes + 7) & ~(size_t)7;
    const size_t csr_bytes  = (size_t)n_edges * sizeof(int2);          // 12.8 MB
    const size_t need       = csr_off + csr_bytes;                     // ~32.5 MB

    bf16* xt   = (bf16*)(ws);
    int*  offs = (int*)(ws + off_off);
    int*  parts= (int*)(ws + part_off);
    int*  rank = (int*)(ws + rank_off);
    int2* csr  = (int2*)(ws + csr_off);

    const bool have_ws = (ws_size >= need);
    const int gemm_blocks = (n_nodes + 63) / 64;   // 1563
    const int hist_blocks = 512;

    if (have_ws) {
        (void)hipMemsetAsync(offs, 0, off_bytes, stream);
        gemm_hist_kernel<<<hist_blocks + gemm_blocks, 256, 0, stream>>>(
            x, weight, ei, xt, offs, rank, n_nodes, n_edges, hist_blocks);

        const int nscan_blocks = (n_nodes + SCAN_B - 1) / SCAN_B;   // 391
        scan1_kernel<<<nscan_blocks, SCAN_B, 0, stream>>>(offs, offs, parts, n_nodes);
        scan23_kernel<<<nscan_blocks, SCAN_B, 0, stream>>>(offs, parts, n_nodes, n_edges);
        fill_kernel<<<(n_edges + 255) / 256, 256, 0, stream>>>(ei, ea, offs, rank, csr, n_edges);

        const int n_waves = (n_nodes + 3) / 4;               // 4 nodes per wave
        const int gth = n_waves * 64;
        gather_kernel<<<(gth + 255) / 256, 256, 0, stream>>>(offs, csr, xt, ewW, ewb,
                                                             bias, out, n_nodes);
    } else {
        gemm_hist_kernel<<<gemm_blocks, 256, 0, stream>>>(x, weight, ei, xt,
                                                          nullptr, nullptr,
                                                          n_nodes, 0, 0);
        int n_f4 = n_nodes * (D / 4);
        init_out_kernel<<<(n_f4 + 255) / 256, 256, 0, stream>>>(out, bias, n_f4);
        edge_atomic_kernel<<<4096, 256, 0, stream>>>(ei, ea, xt, ewW, ewb, out, n_edges);
    }
}